// Round 2
// baseline (513.197 us; speedup 1.0000x reference)
//
#include <hip/hip_runtime.h>
#include <math.h>

#define B_ROWS   1024
#define IN_FEAT  76800
#define OUT_FEAT 10
#define NF4      (IN_FEAT / 4)        // 19200 float4 per row
#define W_ELEMS  (OUT_FEAT * IN_FEAT) // 768000
#define EPSQ     1e-5f
// 19200 = 512*37 + 256 : 37 full 512-thread iterations + one 256-thread tail
#define NJ_FULL  37
#define TAIL_N   256

// ---------------- K1: per-block partial sums of |W| ----------------
__global__ __launch_bounds__(256) void k_wabs_partial(const float* __restrict__ W,
                                                      float* __restrict__ partials) {
    const int tid = threadIdx.x, bid = blockIdx.x;
    float s = 0.f;
    for (int i = bid * 256 + tid; i < W_ELEMS; i += 256 * 256) s += fabsf(W[i]);
    #pragma unroll
    for (int off = 32; off >= 1; off >>= 1) s += __shfl_down(s, off, 64);
    __shared__ float red[4];
    const int wv = tid >> 6, ln = tid & 63;
    if (ln == 0) red[wv] = s;
    __syncthreads();
    if (tid == 0) partials[bid] = red[0] + red[1] + red[2] + red[3];
}

// ---------------- K2: final reduce -> scale_w = 1/clip(mean|W|, eps) ----------------
__global__ __launch_bounds__(256) void k_wscale(const float* __restrict__ partials,
                                                float* __restrict__ scale_w) {
    const int tid = threadIdx.x;
    float s = partials[tid];
    #pragma unroll
    for (int off = 32; off >= 1; off >>= 1) s += __shfl_down(s, off, 64);
    __shared__ float red[4];
    const int wv = tid >> 6, ln = tid & 63;
    if (ln == 0) red[wv] = s;
    __syncthreads();
    if (tid == 0) {
        float mean = (red[0] + red[1] + red[2] + red[3]) / (float)W_ELEMS;
        scale_w[0] = 1.0f / fmaxf(mean, EPSQ);
    }
}

// ---------------- K3: ternary-quantize weights into BYTE planes ----------------
// wq8[o*IN_FEAT + k] = code+1 in {0,1,2}; GEMV decodes with one v_cvt_f32_ubyteN.
__global__ __launch_bounds__(256) void k_wpack8(const float* __restrict__ W,
                                                const float* __restrict__ scale_w,
                                                unsigned char* __restrict__ wq8) {
    const int k = blockIdx.x * 256 + threadIdx.x;
    if (k >= IN_FEAT) return;
    const float s = scale_w[0];
    #pragma unroll
    for (int o = 0; o < OUT_FEAT; ++o) {
        float c = fminf(1.f, fmaxf(-1.f, rintf(W[o * IN_FEAT + k] * s)));
        wq8[o * IN_FEAT + k] = (unsigned char)((int)c + 1);
    }
}

// ---------------- K4: per-row absmax -> sx[row] = 127/clip(max|x|, eps) ----------------
// 512 threads x 1024 blocks = 32 waves/CU: full occupancy HBM stream.
// Side effect: leaves x resident in the 256 MB Infinity Cache for K5.
__global__ __launch_bounds__(512) void k_rowmax(const float* __restrict__ x,
                                                float* __restrict__ sxrow) {
    const int tid = threadIdx.x, row = blockIdx.x;
    const float4* __restrict__ xr = (const float4*)(x + (size_t)row * IN_FEAT);
    float m = 0.f;
    #pragma unroll 4
    for (int j = 0; j < NJ_FULL; ++j) {
        float4 v = xr[tid + j * 512];
        m = fmaxf(m, fmaxf(fmaxf(fabsf(v.x), fabsf(v.y)), fmaxf(fabsf(v.z), fabsf(v.w))));
    }
    if (tid < TAIL_N) {
        float4 v = xr[NJ_FULL * 512 + tid];
        m = fmaxf(m, fmaxf(fmaxf(fabsf(v.x), fabsf(v.y)), fmaxf(fabsf(v.z), fabsf(v.w))));
    }
    #pragma unroll
    for (int off = 32; off >= 1; off >>= 1) m = fmaxf(m, __shfl_down(m, off, 64));
    __shared__ float red[8];
    const int wv = tid >> 6, ln = tid & 63;
    if (ln == 0) red[wv] = m;
    __syncthreads();
    if (tid == 0) {
        float mm = red[0];
        #pragma unroll
        for (int i = 1; i < 8; ++i) mm = fmaxf(mm, red[i]);
        sxrow[row] = 127.0f / fmaxf(mm, EPSQ);
    }
}

// ---------------- K5: quantize + GEMV + bias + softmax, one block per row ----------------
// 512 threads x 1024 blocks = 32 waves/CU. x re-read is L3-resident from K4.
// Byte-plane decode: 1 cvt + 1 fma per (element,output). sum(q*(c+1))-sum(q) = sum(q*c).
__global__ __launch_bounds__(512) void k_gemv(const float* __restrict__ x,
                                              const unsigned char* __restrict__ wq8,
                                              const float* __restrict__ bias,
                                              const float* __restrict__ scale_w,
                                              const float* __restrict__ sxrow,
                                              float* __restrict__ out) {
    __shared__ float racc[8][12];
    __shared__ float fin[12];
    __shared__ float lgs[OUT_FEAT];

    const int tid = threadIdx.x, row = blockIdx.x;
    const float sx = sxrow[row];
    const float sw = scale_w[0];
    const float4* __restrict__ xr = (const float4*)(x + (size_t)row * IN_FEAT);

    float acc[OUT_FEAT] = {0.f, 0.f, 0.f, 0.f, 0.f, 0.f, 0.f, 0.f, 0.f, 0.f};
    float sq = 0.f;

    #pragma unroll 2
    for (int j = 0; j < NJ_FULL; ++j) {
        const int idx = tid + j * 512;
        float4 v = xr[idx];
        float q0 = rintf(v.x * sx);     // |x*sx| <= 127 -> no clamp needed
        float q1 = rintf(v.y * sx);
        float q2 = rintf(v.z * sx);
        float q3 = rintf(v.w * sx);
        sq += (q0 + q1) + (q2 + q3);
        #pragma unroll
        for (int o = 0; o < OUT_FEAT; ++o) {
            unsigned int w = ((const unsigned int*)(wq8 + (size_t)o * IN_FEAT))[idx];
            acc[o] = fmaf(q0, (float)(w & 0xffu),
                     fmaf(q1, (float)((w >> 8) & 0xffu),
                     fmaf(q2, (float)((w >> 16) & 0xffu),
                     fmaf(q3, (float)(w >> 24), acc[o]))));
        }
    }
    if (tid < TAIL_N) {
        const int idx = NJ_FULL * 512 + tid;
        float4 v = xr[idx];
        float q0 = rintf(v.x * sx);
        float q1 = rintf(v.y * sx);
        float q2 = rintf(v.z * sx);
        float q3 = rintf(v.w * sx);
        sq += (q0 + q1) + (q2 + q3);
        #pragma unroll
        for (int o = 0; o < OUT_FEAT; ++o) {
            unsigned int w = ((const unsigned int*)(wq8 + (size_t)o * IN_FEAT))[idx];
            acc[o] = fmaf(q0, (float)(w & 0xffu),
                     fmaf(q1, (float)((w >> 8) & 0xffu),
                     fmaf(q2, (float)((w >> 16) & 0xffu),
                     fmaf(q3, (float)(w >> 24), acc[o]))));
        }
    }

    // ---- block reduce 11 values (10 accs + sum_q) across 8 waves ----
    float vals[11];
    #pragma unroll
    for (int t = 0; t < OUT_FEAT; ++t) vals[t] = acc[t];
    vals[10] = sq;
    #pragma unroll
    for (int t = 0; t < 11; ++t) {
        #pragma unroll
        for (int off = 32; off >= 1; off >>= 1) vals[t] += __shfl_down(vals[t], off, 64);
    }
    const int wv = tid >> 6, ln = tid & 63;
    if (ln == 0) {
        #pragma unroll
        for (int t = 0; t < 11; ++t) racc[wv][t] = vals[t];
    }
    __syncthreads();
    if (tid < 11) {
        float s = 0.f;
        #pragma unroll
        for (int w2 = 0; w2 < 8; ++w2) s += racc[w2][tid];
        fin[tid] = s;
    }
    __syncthreads();
    if (tid < OUT_FEAT) {
        float inv = 1.0f / (sx * sw);   // dequant: sum q*c / (sx*sw)
        lgs[tid] = (fin[tid] - fin[10]) * inv + bias[tid];
    }
    __syncthreads();
    if (tid < OUT_FEAT) {
        float m = lgs[0];
        #pragma unroll
        for (int o = 1; o < OUT_FEAT; ++o) m = fmaxf(m, lgs[o]);
        float den = 0.f;
        #pragma unroll
        for (int o = 0; o < OUT_FEAT; ++o) den += __expf(lgs[o] - m);
        float e = __expf(lgs[tid] - m);
        out[row * OUT_FEAT + tid] = e / den;
    }
}

extern "C" void kernel_launch(void* const* d_in, const int* in_sizes, int n_in,
                              void* d_out, int out_size, void* d_ws, size_t ws_size,
                              hipStream_t stream) {
    const float* x    = (const float*)d_in[0];
    const float* Wmat = (const float*)d_in[1];
    const float* bias = (const float*)d_in[2];
    float* out = (float*)d_out;

    char* wsb = (char*)d_ws;
    float* scale_w      = (float*)wsb;                   // 1 float
    float* partials     = (float*)(wsb + 256);           // 256 floats
    float* sxrow        = (float*)(wsb + 4096);          // 1024 floats
    unsigned char* wq8  = (unsigned char*)(wsb + 8192);  // 768000 bytes (10 planes)

    k_wabs_partial<<<256, 256, 0, stream>>>(Wmat, partials);
    k_wscale<<<1, 256, 0, stream>>>(partials, scale_w);
    k_wpack8<<<(IN_FEAT + 255) / 256, 256, 0, stream>>>(Wmat, scale_w, wq8);
    k_rowmax<<<B_ROWS, 512, 0, stream>>>(x, sxrow);      // right before gemv: L3 freshness
    k_gemv<<<B_ROWS, 512, 0, stream>>>(x, wq8, bias, scale_w, sxrow, out);
}

// Round 3
// 493.651 us; speedup vs baseline: 1.0396x; 1.0396x over previous
//
#include <hip/hip_runtime.h>
#include <math.h>

#define B_ROWS   1024
#define IN_FEAT  76800
#define OUT_FEAT 10
#define NF4      (IN_FEAT / 4)        // 19200 float4 per row
#define W_ELEMS  (OUT_FEAT * IN_FEAT) // 768000
#define EPSQ     1e-5f
// rowmax: 19200 = 512*37 + 256
#define NJ_FULL  37
#define TAIL_N   256
// gemv: k split into 4 chunks of 4800 float4 (19200 elements); R=2 rows per block
#define CH4      4800
#define NCHUNK   4
#define RPB      2

// ---------------- K1: per-block partial sums of |W| ----------------
__global__ __launch_bounds__(256) void k_wabs_partial(const float* __restrict__ W,
                                                      float* __restrict__ partials) {
    const int tid = threadIdx.x, bid = blockIdx.x;
    float s = 0.f;
    for (int i = bid * 256 + tid; i < W_ELEMS; i += 256 * 256) s += fabsf(W[i]);
    #pragma unroll
    for (int off = 32; off >= 1; off >>= 1) s += __shfl_down(s, off, 64);
    __shared__ float red[4];
    const int wv = tid >> 6, ln = tid & 63;
    if (ln == 0) red[wv] = s;
    __syncthreads();
    if (tid == 0) partials[bid] = red[0] + red[1] + red[2] + red[3];
}

// ---------------- K2: final reduce -> scale_w = 1/clip(mean|W|, eps) ----------------
__global__ __launch_bounds__(256) void k_wscale(const float* __restrict__ partials,
                                                float* __restrict__ scale_w) {
    const int tid = threadIdx.x;
    float s = partials[tid];
    #pragma unroll
    for (int off = 32; off >= 1; off >>= 1) s += __shfl_down(s, off, 64);
    __shared__ float red[4];
    const int wv = tid >> 6, ln = tid & 63;
    if (ln == 0) red[wv] = s;
    __syncthreads();
    if (tid == 0) {
        float mean = (red[0] + red[1] + red[2] + red[3]) / (float)W_ELEMS;
        scale_w[0] = 1.0f / fmaxf(mean, EPSQ);
    }
}

// ---------------- K3: ternary-quantize + pack weights, 2 bits/output ----------------
// wpack[k] bits [2o+1:2o] = (code+1) in {0,1,2}. 4 B/k -> total weight stream for the
// whole GEMV is 78 MB (vs 786 MB with byte planes re-read per row-block).
__global__ __launch_bounds__(256) void k_wpack(const float* __restrict__ W,
                                               const float* __restrict__ scale_w,
                                               unsigned int* __restrict__ wpack) {
    const int k = blockIdx.x * 256 + threadIdx.x;
    if (k >= IN_FEAT) return;
    const float s = scale_w[0];
    unsigned int u = 0;
    #pragma unroll
    for (int o = 0; o < OUT_FEAT; ++o) {
        float c = fminf(1.f, fmaxf(-1.f, rintf(W[o * IN_FEAT + k] * s)));
        u |= (unsigned int)((int)c + 1) << (2 * o);
    }
    wpack[k] = u;
}

// ---------------- K4: per-row absmax + zero the row's accumulator ----------------
// 512 thr x 1024 blocks = full-occupancy HBM stream; leaves x hot in L3 for K5.
__global__ __launch_bounds__(512) void k_rowmax(const float* __restrict__ x,
                                                float* __restrict__ sxrow,
                                                float* __restrict__ accum) {
    const int tid = threadIdx.x, row = blockIdx.x;
    const float4* __restrict__ xr = (const float4*)(x + (size_t)row * IN_FEAT);
    if (tid < 12) accum[row * 12 + tid] = 0.f;   // workspace is re-poisoned each iter
    float m = 0.f;
    #pragma unroll 4
    for (int j = 0; j < NJ_FULL; ++j) {
        float4 v = xr[tid + j * 512];
        m = fmaxf(m, fmaxf(fmaxf(fabsf(v.x), fabsf(v.y)), fmaxf(fabsf(v.z), fabsf(v.w))));
    }
    if (tid < TAIL_N) {
        float4 v = xr[NJ_FULL * 512 + tid];
        m = fmaxf(m, fmaxf(fmaxf(fabsf(v.x), fabsf(v.y)), fmaxf(fabsf(v.z), fabsf(v.w))));
    }
    #pragma unroll
    for (int off = 32; off >= 1; off >>= 1) m = fmaxf(m, __shfl_down(m, off, 64));
    __shared__ float red[8];
    const int wv = tid >> 6, ln = tid & 63;
    if (ln == 0) red[wv] = m;
    __syncthreads();
    if (tid == 0) {
        float mm = red[0];
        #pragma unroll
        for (int i = 1; i < 8; ++i) mm = fmaxf(mm, red[i]);
        sxrow[row] = 127.0f / fmaxf(mm, EPSQ);
    }
}

// ---------------- K5: quantize + partial GEMV, 2 rows x 1/4 row per block ----------------
// Weights (2-bit pack) decoded once per k, shared by both rows (compiler CSEs the bfe/cvt).
// Partial sums are integer-valued fp32 (< 2^23 per block) -> atomicAdd is exact and
// order-independent. 2048 blocks x 512 thr = 32 waves/CU if VGPR allows.
__device__ __forceinline__ void proc1(float xv, unsigned int w, float sx,
                                      float* acc, float& sq) {
    float q = rintf(xv * sx);   // |x*sx| <= 127 -> no clamp needed
    sq += q;
    #pragma unroll
    for (int o = 0; o < OUT_FEAT; ++o)
        acc[o] = fmaf(q, (float)((w >> (2 * o)) & 3u), acc[o]);
}

__global__ __launch_bounds__(512) void k_gemv(const float* __restrict__ x,
                                              const unsigned int* __restrict__ wpack,
                                              const float* __restrict__ sxrow,
                                              float* __restrict__ accum) {
    const int tid = threadIdx.x;
    const int rg  = blockIdx.x >> 2;          // row group (0..511)
    const int c   = blockIdx.x & 3;           // k chunk   (0..3)
    const int row0 = rg * RPB, row1 = row0 + 1;
    const float sx0 = sxrow[row0], sx1 = sxrow[row1];
    const float4* __restrict__ x0 = (const float4*)(x + (size_t)row0 * IN_FEAT);
    const float4* __restrict__ x1 = (const float4*)(x + (size_t)row1 * IN_FEAT);
    const uint4*  __restrict__ wp4 = (const uint4*)wpack;
    const int cbase = c * CH4, cend = cbase + CH4;

    float acc0[OUT_FEAT] = {0.f,0.f,0.f,0.f,0.f,0.f,0.f,0.f,0.f,0.f};
    float acc1[OUT_FEAT] = {0.f,0.f,0.f,0.f,0.f,0.f,0.f,0.f,0.f,0.f};
    float sq0 = 0.f, sq1 = 0.f;

    #pragma unroll 2
    for (int j = 0; j < 10; ++j) {            // 4800 = 512*9 + 192
        const int idx = cbase + tid + j * 512;
        if (idx < cend) {
            uint4  w = wp4[idx];
            float4 a = x0[idx];
            float4 b = x1[idx];
            proc1(a.x, w.x, sx0, acc0, sq0);  proc1(b.x, w.x, sx1, acc1, sq1);
            proc1(a.y, w.y, sx0, acc0, sq0);  proc1(b.y, w.y, sx1, acc1, sq1);
            proc1(a.z, w.z, sx0, acc0, sq0);  proc1(b.z, w.z, sx1, acc1, sq1);
            proc1(a.w, w.w, sx0, acc0, sq0);  proc1(b.w, w.w, sx1, acc1, sq1);
        }
    }

    // ---- block reduce 22 values (2 rows x (10 accs + sum_q)) ----
    float vals[22];
    #pragma unroll
    for (int t = 0; t < OUT_FEAT; ++t) { vals[t] = acc0[t]; vals[11 + t] = acc1[t]; }
    vals[10] = sq0; vals[21] = sq1;
    #pragma unroll
    for (int t = 0; t < 22; ++t) {
        #pragma unroll
        for (int off = 32; off >= 1; off >>= 1) vals[t] += __shfl_down(vals[t], off, 64);
    }
    __shared__ float racc[8][22];
    const int wv = tid >> 6, ln = tid & 63;
    if (ln == 0) {
        #pragma unroll
        for (int t = 0; t < 22; ++t) racc[wv][t] = vals[t];
    }
    __syncthreads();
    if (tid < 22) {
        float s = 0.f;
        #pragma unroll
        for (int w2 = 0; w2 < 8; ++w2) s += racc[w2][tid];
        const int r = (tid < 11) ? row0 : row1;
        const int t = (tid < 11) ? tid  : tid - 11;
        atomicAdd(&accum[r * 12 + t], s);     // exact: integer-valued floats
    }
}

// ---------------- K6: dequant + bias + softmax ----------------
__global__ __launch_bounds__(64) void k_fin(const float* __restrict__ accum,
                                            const float* __restrict__ bias,
                                            const float* __restrict__ scale_w,
                                            const float* __restrict__ sxrow,
                                            float* __restrict__ out) {
    const int row = blockIdx.x, tid = threadIdx.x;
    __shared__ float lgs[OUT_FEAT];
    const float inv = 1.0f / (sxrow[row] * scale_w[0]);
    if (tid < OUT_FEAT) {
        // sum q*(c+1) - sum q = sum q*c ; dequant by 1/(sx*sw)
        lgs[tid] = (accum[row * 12 + tid] - accum[row * 12 + 10]) * inv + bias[tid];
    }
    __syncthreads();
    if (tid < OUT_FEAT) {
        float m = lgs[0];
        #pragma unroll
        for (int o = 1; o < OUT_FEAT; ++o) m = fmaxf(m, lgs[o]);
        float den = 0.f;
        #pragma unroll
        for (int o = 0; o < OUT_FEAT; ++o) den += __expf(lgs[o] - m);
        float e = __expf(lgs[tid] - m);
        out[row * OUT_FEAT + tid] = e / den;
    }
}

extern "C" void kernel_launch(void* const* d_in, const int* in_sizes, int n_in,
                              void* d_out, int out_size, void* d_ws, size_t ws_size,
                              hipStream_t stream) {
    const float* x    = (const float*)d_in[0];
    const float* Wmat = (const float*)d_in[1];
    const float* bias = (const float*)d_in[2];
    float* out = (float*)d_out;

    char* wsb = (char*)d_ws;
    float* scale_w      = (float*)wsb;                    // 1 float
    float* partials     = (float*)(wsb + 256);            // 256 floats
    float* sxrow        = (float*)(wsb + 4096);           // 1024 floats
    float* accum        = (float*)(wsb + 8192);           // 1024*12 floats = 48 KB
    unsigned int* wpack = (unsigned int*)(wsb + 65536);   // 76800 uint32 = 307 KB

    k_wabs_partial<<<256, 256, 0, stream>>>(Wmat, partials);
    k_wscale<<<1, 256, 0, stream>>>(partials, scale_w);
    k_wpack<<<(IN_FEAT + 255) / 256, 256, 0, stream>>>(Wmat, scale_w, wpack);
    k_rowmax<<<B_ROWS, 512, 0, stream>>>(x, sxrow, accum);   // also zeroes accum
    k_gemv<<<(B_ROWS / RPB) * NCHUNK, 512, 0, stream>>>(x, wpack, sxrow, accum);
    k_fin<<<B_ROWS, 64, 0, stream>>>(accum, bias, scale_w, sxrow, out);
}

// Round 4
// 488.535 us; speedup vs baseline: 1.0505x; 1.0105x over previous
//
#include <hip/hip_runtime.h>
#include <math.h>

#define B_ROWS   1024
#define IN_FEAT  76800
#define OUT_FEAT 10
#define NF4      (IN_FEAT / 4)        // 19200 float4 per row
#define W_ELEMS  (OUT_FEAT * IN_FEAT) // 768000
#define EPSQ     1e-5f
// rowmax: 19200 = 512*37 + 256
#define NJ_FULL  37
#define TAIL_N   256
// gemv: k split into 4 chunks of 4800 float4 (19200 elements); R=2 rows per block
#define CH4      4800
#define NCHUNK   4
#define RPB      2

// ---------------- K1: per-block partial sums of |W| ----------------
__global__ __launch_bounds__(256) void k_wabs_partial(const float* __restrict__ W,
                                                      float* __restrict__ partials) {
    const int tid = threadIdx.x, bid = blockIdx.x;
    float s = 0.f;
    for (int i = bid * 256 + tid; i < W_ELEMS; i += 256 * 256) s += fabsf(W[i]);
    #pragma unroll
    for (int off = 32; off >= 1; off >>= 1) s += __shfl_down(s, off, 64);
    __shared__ float red[4];
    const int wv = tid >> 6, ln = tid & 63;
    if (ln == 0) red[wv] = s;
    __syncthreads();
    if (tid == 0) partials[bid] = red[0] + red[1] + red[2] + red[3];
}

// ---------------- K2: final reduce -> scale_w = 1/clip(mean|W|, eps) ----------------
__global__ __launch_bounds__(256) void k_wscale(const float* __restrict__ partials,
                                                float* __restrict__ scale_w) {
    const int tid = threadIdx.x;
    float s = partials[tid];
    #pragma unroll
    for (int off = 32; off >= 1; off >>= 1) s += __shfl_down(s, off, 64);
    __shared__ float red[4];
    const int wv = tid >> 6, ln = tid & 63;
    if (ln == 0) red[wv] = s;
    __syncthreads();
    if (tid == 0) {
        float mean = (red[0] + red[1] + red[2] + red[3]) / (float)W_ELEMS;
        scale_w[0] = 1.0f / fmaxf(mean, EPSQ);
    }
}

// ---------------- K3: ternary-quantize + pack weights, 2 bits/output ----------------
// wpack[k] bits [2o+1:2o] = (code+1) in {0,1,2}. 4 B/k; wpack (307 KB) stays
// L2-resident during the GEMV, so weight re-reads are cheap.
__global__ __launch_bounds__(256) void k_wpack(const float* __restrict__ W,
                                               const float* __restrict__ scale_w,
                                               unsigned int* __restrict__ wpack) {
    const int k = blockIdx.x * 256 + threadIdx.x;
    if (k >= IN_FEAT) return;
    const float s = scale_w[0];
    unsigned int u = 0;
    #pragma unroll
    for (int o = 0; o < OUT_FEAT; ++o) {
        float c = fminf(1.f, fmaxf(-1.f, rintf(W[o * IN_FEAT + k] * s)));
        u |= (unsigned int)((int)c + 1) << (2 * o);
    }
    wpack[k] = u;
}

// ---------------- K4: per-row absmax + zero the row's accumulator ----------------
// Streams rows 0->1023 from HBM. At completion the LAST ~256 MB (rows ~169..1023)
// are Infinity-Cache resident -> K5 consumes rows in DESCENDING order to hit them.
__global__ __launch_bounds__(512) void k_rowmax(const float* __restrict__ x,
                                                float* __restrict__ sxrow,
                                                float* __restrict__ accum) {
    const int tid = threadIdx.x, row = blockIdx.x;
    const float4* __restrict__ xr = (const float4*)(x + (size_t)row * IN_FEAT);
    if (tid < 12) accum[row * 12 + tid] = 0.f;   // workspace is re-poisoned each iter
    float m = 0.f;
    #pragma unroll 4
    for (int j = 0; j < NJ_FULL; ++j) {
        float4 v = xr[tid + j * 512];
        m = fmaxf(m, fmaxf(fmaxf(fabsf(v.x), fabsf(v.y)), fmaxf(fabsf(v.z), fabsf(v.w))));
    }
    if (tid < TAIL_N) {
        float4 v = xr[NJ_FULL * 512 + tid];
        m = fmaxf(m, fmaxf(fmaxf(fabsf(v.x), fabsf(v.y)), fmaxf(fabsf(v.z), fabsf(v.w))));
    }
    #pragma unroll
    for (int off = 32; off >= 1; off >>= 1) m = fmaxf(m, __shfl_down(m, off, 64));
    __shared__ float red[8];
    const int wv = tid >> 6, ln = tid & 63;
    if (ln == 0) red[wv] = m;
    __syncthreads();
    if (tid == 0) {
        float mm = red[0];
        #pragma unroll
        for (int i = 1; i < 8; ++i) mm = fmaxf(mm, red[i]);
        sxrow[row] = 127.0f / fmaxf(mm, EPSQ);
    }
}

// ---------------- K5: quantize + partial GEMV, 2 rows x 1/4 row per block ----------------
// ROW ORDER REVERSED vs dispatch order: early blocks (low blockIdx, dispatched first)
// process HIGH rows — the ones still L3-resident from k_rowmax's tail. L3 hits refresh
// LRU without evicting, so mid rows survive for later blocks; only rows ~0..168 miss.
// Weights (2-bit pack) decoded once per k, shared by both rows. Partial sums are
// integer-valued fp32 (< 2^23) -> atomicAdd is exact and order-independent.
__device__ __forceinline__ void proc1(float xv, unsigned int w, float sx,
                                      float* acc, float& sq) {
    float q = rintf(xv * sx);   // |x*sx| <= 127 -> no clamp needed
    sq += q;
    #pragma unroll
    for (int o = 0; o < OUT_FEAT; ++o)
        acc[o] = fmaf(q, (float)((w >> (2 * o)) & 3u), acc[o]);
}

__global__ __launch_bounds__(512) void k_gemv(const float* __restrict__ x,
                                              const unsigned int* __restrict__ wpack,
                                              const float* __restrict__ sxrow,
                                              float* __restrict__ accum) {
    const int tid = threadIdx.x;
    const int rg  = (B_ROWS / RPB - 1) - (blockIdx.x >> 2);  // REVERSED row group
    const int c   = blockIdx.x & 3;                          // k chunk (0..3)
    const int row0 = rg * RPB, row1 = row0 + 1;
    const float sx0 = sxrow[row0], sx1 = sxrow[row1];
    const float4* __restrict__ x0 = (const float4*)(x + (size_t)row0 * IN_FEAT);
    const float4* __restrict__ x1 = (const float4*)(x + (size_t)row1 * IN_FEAT);
    const uint4*  __restrict__ wp4 = (const uint4*)wpack;
    const int cbase = c * CH4, cend = cbase + CH4;

    float acc0[OUT_FEAT] = {0.f,0.f,0.f,0.f,0.f,0.f,0.f,0.f,0.f,0.f};
    float acc1[OUT_FEAT] = {0.f,0.f,0.f,0.f,0.f,0.f,0.f,0.f,0.f,0.f};
    float sq0 = 0.f, sq1 = 0.f;

    #pragma unroll 2
    for (int j = 0; j < 10; ++j) {            // 4800 = 512*9 + 192
        const int idx = cbase + tid + j * 512;
        if (idx < cend) {
            uint4  w = wp4[idx];
            float4 a = x0[idx];
            float4 b = x1[idx];
            proc1(a.x, w.x, sx0, acc0, sq0);  proc1(b.x, w.x, sx1, acc1, sq1);
            proc1(a.y, w.y, sx0, acc0, sq0);  proc1(b.y, w.y, sx1, acc1, sq1);
            proc1(a.z, w.z, sx0, acc0, sq0);  proc1(b.z, w.z, sx1, acc1, sq1);
            proc1(a.w, w.w, sx0, acc0, sq0);  proc1(b.w, w.w, sx1, acc1, sq1);
        }
    }

    // ---- block reduce 22 values (2 rows x (10 accs + sum_q)) ----
    float vals[22];
    #pragma unroll
    for (int t = 0; t < OUT_FEAT; ++t) { vals[t] = acc0[t]; vals[11 + t] = acc1[t]; }
    vals[10] = sq0; vals[21] = sq1;
    #pragma unroll
    for (int t = 0; t < 22; ++t) {
        #pragma unroll
        for (int off = 32; off >= 1; off >>= 1) vals[t] += __shfl_down(vals[t], off, 64);
    }
    __shared__ float racc[8][22];
    const int wv = tid >> 6, ln = tid & 63;
    if (ln == 0) {
        #pragma unroll
        for (int t = 0; t < 22; ++t) racc[wv][t] = vals[t];
    }
    __syncthreads();
    if (tid < 22) {
        float s = 0.f;
        #pragma unroll
        for (int w2 = 0; w2 < 8; ++w2) s += racc[w2][tid];
        const int r = (tid < 11) ? row0 : row1;
        const int t = (tid < 11) ? tid  : tid - 11;
        atomicAdd(&accum[r * 12 + t], s);     // exact: integer-valued floats
    }
}

// ---------------- K6: dequant + bias + softmax ----------------
__global__ __launch_bounds__(64) void k_fin(const float* __restrict__ accum,
                                            const float* __restrict__ bias,
                                            const float* __restrict__ scale_w,
                                            const float* __restrict__ sxrow,
                                            float* __restrict__ out) {
    const int row = blockIdx.x, tid = threadIdx.x;
    __shared__ float lgs[OUT_FEAT];
    const float inv = 1.0f / (sxrow[row] * scale_w[0]);
    if (tid < OUT_FEAT) {
        // sum q*(c+1) - sum q = sum q*c ; dequant by 1/(sx*sw)
        lgs[tid] = (accum[row * 12 + tid] - accum[row * 12 + 10]) * inv + bias[tid];
    }
    __syncthreads();
    if (tid < OUT_FEAT) {
        float m = lgs[0];
        #pragma unroll
        for (int o = 1; o < OUT_FEAT; ++o) m = fmaxf(m, lgs[o]);
        float den = 0.f;
        #pragma unroll
        for (int o = 0; o < OUT_FEAT; ++o) den += __expf(lgs[o] - m);
        float e = __expf(lgs[tid] - m);
        out[row * OUT_FEAT + tid] = e / den;
    }
}

extern "C" void kernel_launch(void* const* d_in, const int* in_sizes, int n_in,
                              void* d_out, int out_size, void* d_ws, size_t ws_size,
                              hipStream_t stream) {
    const float* x    = (const float*)d_in[0];
    const float* Wmat = (const float*)d_in[1];
    const float* bias = (const float*)d_in[2];
    float* out = (float*)d_out;

    char* wsb = (char*)d_ws;
    float* scale_w      = (float*)wsb;                    // 1 float
    float* partials     = (float*)(wsb + 256);            // 256 floats
    float* sxrow        = (float*)(wsb + 4096);           // 1024 floats
    float* accum        = (float*)(wsb + 8192);           // 1024*12 floats = 48 KB
    unsigned int* wpack = (unsigned int*)(wsb + 65536);   // 76800 uint32 = 307 KB

    k_wabs_partial<<<256, 256, 0, stream>>>(Wmat, partials);
    k_wscale<<<1, 256, 0, stream>>>(partials, scale_w);
    k_wpack<<<(IN_FEAT + 255) / 256, 256, 0, stream>>>(Wmat, scale_w, wpack);
    k_rowmax<<<B_ROWS, 512, 0, stream>>>(x, sxrow, accum);   // also zeroes accum
    k_gemv<<<(B_ROWS / RPB) * NCHUNK, 512, 0, stream>>>(x, wpack, sxrow, accum);
    k_fin<<<B_ROWS, 64, 0, stream>>>(accum, bias, scale_w, sxrow, out);
}